// Round 8
// baseline (132.643 us; speedup 1.0000x reference)
//
#include <hip/hip_runtime.h>
#include <math.h>

#define QDEPTH 6

typedef _Float16 h2 __attribute__((ext_vector_type(2)));
typedef _Float16 v8h __attribute__((ext_vector_type(8)));
typedef float    v4f __attribute__((ext_vector_type(4)));
typedef unsigned uu4 __attribute__((ext_vector_type(4)));

__device__ __forceinline__ int   h2i(h2 v)  { return __builtin_bit_cast(int, v); }
__device__ __forceinline__ h2    ih2(int v) { return __builtin_bit_cast(h2, v); }
__device__ __forceinline__ unsigned h2u(h2 v) { return __builtin_bit_cast(unsigned, v); }

__device__ __forceinline__ h2 bper(int addr, h2 v) {
  return ih2(__builtin_amdgcn_ds_bpermute(addr, h2i(v)));
}

template<int CTRL>
__device__ __forceinline__ h2 dpph(h2 v) {
  int i = h2i(v);
  return ih2(__builtin_amdgcn_update_dpp(i, i, CTRL, 0xF, 0xF, true));
}

template<int CTRL>
__device__ __forceinline__ float dpp_add0(float v) {
  int i = __float_as_int(v);
  int r = __builtin_amdgcn_update_dpp(0, i, CTRL, 0xF, 0xF, false);
  return v + __int_as_float(r);
}

// full-wave sum; result valid in lane 63
__device__ __forceinline__ float wave_sum(float v) {
  v = dpp_add0<0x111>(v);
  v = dpp_add0<0x112>(v);
  v = dpp_add0<0x114>(v);
  v = dpp_add0<0x118>(v);
  v = dpp_add0<0x142>(v);
  v = dpp_add0<0x143>(v);
  return v;
}

__device__ __forceinline__ float bcast63(float v) {
  return __int_as_float(__builtin_amdgcn_readlane(__float_as_int(v), 63));
}

__device__ __forceinline__ void pl32s(int& a, int& b) {
  asm("v_permlane32_swap_b32 %0, %1" : "+v"(a), "+v"(b));
}
__device__ __forceinline__ void pl16s(int& a, int& b) {
  asm("v_permlane16_swap_b32 %0, %1" : "+v"(a), "+v"(b));
}

// ---- shared circuit-layer engine (verified in R5-R7), state x[8] h2 ----
// amp index (10 bits) = lane(6)<<4 | r(3)<<1 | half(1); wires 0..5 = lane bits
// 5..0, wires 6,7,8 = r bits 2..0 (A2 A1 A0), wire 9 = packed half.
__device__ __forceinline__ void apply_layers(h2 (&x)[8], const unsigned* sco,
                                             int lane, int addrP, int addrX4,
                                             bool cb1) {
  for (int k = 0; k < QDEPTH; ++k) {
    const unsigned* L = sco + k * 29;
#pragma unroll
    for (int i = 0; i < 8; ++i) x[i] = bper(addrP, x[i]);
    { h2 t = x[4]; x[4] = x[6]; x[6] = t; t = x[5]; x[5] = x[7]; x[7] = t; }
    { h2 t = x[2]; x[2] = x[3]; x[3] = t; t = x[6]; x[6] = x[7]; x[7] = t; }
    { h2 cc9 = ih2(L[27]), ms9 = ih2(L[28]);
#pragma unroll
      for (int i = 0; i < 8; ++i) {
        h2 t = __builtin_shufflevector(x[i], x[i], 1, 0);
        bool flg = (i == 1 || i == 2 || i == 5 || i == 6);
        x[i] = flg ? (h2)(t * cc9 + x[i] * ms9) : (h2)(x[i] * cc9 + t * ms9);
      } }
    { h2 cc6 = ih2(L[18]), ss6 = ih2(L[19]), ns6 = ih2(L[20]);
      h2 AA = cb1 ? ns6 : cc6;
      h2 BB = cb1 ? cc6 : ns6;
      h2 CC = cb1 ? cc6 : ss6;
      h2 DD = cb1 ? ss6 : cc6;
#pragma unroll
      for (int i = 0; i < 4; ++i) {
        h2 u = x[i], w = x[i + 4];
        x[i]     = u * AA + w * BB;
        x[i + 4] = u * CC + w * DD;
      } }
    { h2 cc7 = ih2(L[21]), ss7 = ih2(L[22]), ns7 = ih2(L[23]);
#pragma unroll
      for (int i = 0; i < 8; ++i) if (!(i & 2)) {
        h2 u = x[i], w = x[i | 2];
        x[i]     = u * cc7 + w * ns7;
        x[i | 2] = w * cc7 + u * ss7;
      } }
    { h2 cc8 = ih2(L[24]), ss8 = ih2(L[25]), ns8 = ih2(L[26]);
#pragma unroll
      for (int i = 0; i < 8; ++i) if (!(i & 1)) {
        h2 u = x[i], w = x[i | 1];
        x[i]     = u * cc8 + w * ns8;
        x[i | 1] = w * cc8 + u * ss8;
      } }
    { h2 cc0 = ih2(L[0]), ss0 = ih2(L[1]), ns0 = ih2(L[2]);
#pragma unroll
      for (int j = 0; j < 4; ++j) {
        int a = h2i(x[2 * j]), b = h2i(x[2 * j + 1]);
        pl32s(a, b);
        h2 u = ih2(a), v = ih2(b);
        h2 nu = u * cc0 + v * ns0;
        h2 nv = v * cc0 + u * ss0;
        int na = h2i(nu), nb = h2i(nv);
        pl32s(na, nb);
        x[2 * j] = ih2(na); x[2 * j + 1] = ih2(nb);
      } }
    { h2 cc1 = ih2(L[3]), ss1 = ih2(L[4]), ns1 = ih2(L[5]);
#pragma unroll
      for (int j = 0; j < 4; ++j) {
        int a = h2i(x[2 * j]), b = h2i(x[2 * j + 1]);
        pl16s(a, b);
        h2 u = ih2(a), v = ih2(b);
        h2 nu = u * cc1 + v * ns1;
        h2 nv = v * cc1 + u * ss1;
        int na = h2i(nu), nb = h2i(nv);
        pl16s(na, nb);
        x[2 * j] = ih2(na); x[2 * j + 1] = ih2(nb);
      } }
    { h2 cc2 = ih2(L[6]), ss2 = ih2(L[7]), ns2 = ih2(L[8]);
      h2 gg = (lane & 8) ? ss2 : ns2;
#pragma unroll
      for (int i = 0; i < 8; ++i) {
        h2 p = dpph<0x128>(x[i]);
        x[i] = x[i] * cc2 + p * gg;
      } }
    { h2 cc3 = ih2(L[9]), ss3 = ih2(L[10]), ns3 = ih2(L[11]);
      h2 gg = (lane & 4) ? ss3 : ns3;
#pragma unroll
      for (int i = 0; i < 8; ++i) {
        h2 p = bper(addrX4, x[i]);
        x[i] = x[i] * cc3 + p * gg;
      } }
    { h2 cc4 = ih2(L[12]), ss4 = ih2(L[13]), ns4 = ih2(L[14]);
      h2 gg = (lane & 2) ? ss4 : ns4;
#pragma unroll
      for (int i = 0; i < 8; ++i) {
        h2 p = dpph<0x4E>(x[i]);
        x[i] = x[i] * cc4 + p * gg;
      } }
    { h2 cc5 = ih2(L[15]), ss5 = ih2(L[16]), ns5 = ih2(L[17]);
      h2 gg = (lane & 1) ? ss5 : ns5;
#pragma unroll
      for (int i = 0; i < 8; ++i) {
        h2 p = dpph<0xB1>(x[i]);
        x[i] = x[i] * cc5 + p * gg;
      } }
  }
}

__device__ __forceinline__ void fill_sco(const float* qp, unsigned* sco) {
  int t = threadIdx.x;
  if (t < 60) {
    int k = t / 10, w = t % 10;
    float ang = qp[(k + 1) * 10 + w] * 0.5f;
    float c = __cosf(ang), s = __sinf(ang);
    _Float16 ch = (_Float16)c, sh = (_Float16)s, nh = (_Float16)(-s);
    if (w < 9) {
      sco[k * 29 + w * 3 + 0] = h2u((h2){ch, ch});
      sco[k * 29 + w * 3 + 1] = h2u((h2){sh, sh});
      sco[k * 29 + w * 3 + 2] = h2u((h2){nh, nh});
    } else {
      sco[k * 29 + 27] = h2u((h2){ch, ch});
      sco[k * 29 + 28] = h2u((h2){nh, sh});
    }
  }
}

// ============ kernel 1: build U^T (swizzled B-tiles) + w-tables ============
// basis i per wave (1024 waves). B[k=i][n] = (U e_i)[n], stored in 32x16 f16
// tiles: tile(kt,nt) base = (nt*32+kt)*512 f16; slot = ((kk>>3)<<4 | nn)*8 + (kk&7).
__global__ void __launch_bounds__(256) build_kernel(
    const float* __restrict__ qp, const float* __restrict__ Wpost,
    unsigned short* __restrict__ Bswz, float* __restrict__ w0,
    float* __restrict__ w1) {
  __shared__ unsigned sco[QDEPTH * 29];
  fill_sco(qp, sco);
  __syncthreads();

  int lane = threadIdx.x & 63;
  int i = blockIdx.x * 4 + (threadIdx.x >> 6);  // basis index 0..1023

  if (blockIdx.x == 0) {
    for (int n = threadIdx.x; n < 1024; n += 256) {
      float a0 = 0.f, a1 = 0.f;
#pragma unroll
      for (int w = 0; w < 10; ++w) {
        float sg = ((n >> (9 - w)) & 1) ? -1.f : 1.f;
        a0 += sg * Wpost[w];
        a1 += sg * Wpost[10 + w];
      }
      w0[n] = a0; w1[n] = a1;
    }
  }

  int o = lane ^ (((lane >> 4) & 1) << 3) ^ (((lane >> 2) & 1) << 1);
  int psrc = o ^ (((o >> 5) & 1) << 4) ^ (((o >> 3) & 1) << 2) ^ ((o >> 1) & 1);
  int addrP = psrc << 2, addrX4 = (lane ^ 4) << 2;
  bool cb1 = lane & 1;

  h2 x[8];
#pragma unroll
  for (int r = 0; r < 8; ++r) {
    int base = lane * 16 + 2 * r;
    x[r] = (h2){ (_Float16)(base == i ? 1.f : 0.f),
                 (_Float16)(base + 1 == i ? 1.f : 0.f) };
  }

  apply_layers(x, sco, lane, addrP, addrX4, cb1);

  int kt = i >> 5, kk = i & 31;
  int jj = kk & 7, hi16 = (kk >> 3) << 4;
  size_t tbase = ((size_t)(lane * 32 + kt)) << 9;  // tile base in f16 units
#pragma unroll
  for (int r = 0; r < 8; ++r) {
    unsigned u = h2u(x[r]);
    Bswz[tbase + (size_t)((hi16 | (2 * r)) * 8 + jj)]     = (unsigned short)(u & 0xFFFF);
    Bswz[tbase + (size_t)((hi16 | (2 * r + 1)) * 8 + jj)] = (unsigned short)(u >> 16);
  }
}

// ============ kernel 2: pre-GEMM + init factors -> glane/greg tables ============
__global__ void __launch_bounds__(256) glgr_kernel(
    const float* __restrict__ inp, const float* __restrict__ Wred,
    const float* __restrict__ bred, const float* __restrict__ bpost,
    unsigned short* __restrict__ glane, unsigned short* __restrict__ greg,
    float* __restrict__ out) {
  int tid  = blockIdx.x * 256 + threadIdx.x;
  int wv   = tid >> 6;
  int lane = tid & 63;

  const float4* rA = (const float4*)(inp + (size_t)(2 * wv) * 512);
  const float4* rB = (const float4*)(inp + (size_t)(2 * wv + 1) * 512);
  float4 A0 = rA[lane], A1 = rA[lane + 64];
  float4 B0 = rB[lane], B1 = rB[lane + 64];
  float thA[10], thB[10];
#pragma unroll
  for (int q = 0; q < 10; ++q) {
    const float4* w4 = (const float4*)(Wred + q * 512);
    float4 w0v = w4[lane], w1v = w4[lane + 64];
    thA[q] = A0.x * w0v.x + A0.y * w0v.y + A0.z * w0v.z + A0.w * w0v.w
           + A1.x * w1v.x + A1.y * w1v.y + A1.z * w1v.z + A1.w * w1v.w;
    thB[q] = B0.x * w0v.x + B0.y * w0v.y + B0.z * w0v.z + B0.w * w0v.w
           + B1.x * w1v.x + B1.y * w1v.y + B1.z * w1v.z + B1.w * w1v.w;
  }

#pragma unroll
  for (int e = 0; e < 2; ++e) {
    int el = 2 * wv + e;
    float g0[10], g1[10];
#pragma unroll
    for (int q = 0; q < 10; ++q) {
      float tot = bcast63(wave_sum(e ? thB[q] : thA[q])) + bred[q];
      float xc = fminf(fmaxf(tot, -15.f), 15.f);
      float u = __expf(2.f * xc);
      float tanhv = (u - 1.f) * __builtin_amdgcn_rcpf(u + 1.f);
      float t = tanhv * 0.78539816339744831f;
      float c = __cosf(t), s = __sinf(t);
      g0[q] = (c - s) * 0.70710678118654752f;
      g1[q] = (c + s) * 0.70710678118654752f;
    }
    float lf = 1.f;
#pragma unroll
    for (int w = 0; w < 6; ++w)
      lf *= ((lane >> (5 - w)) & 1) ? g1[w] : g0[w];
    glane[(size_t)el * 64 + lane] =
        (unsigned short)(h2u((h2){(_Float16)lf, (_Float16)lf}) & 0xFFFF);
    if (lane < 16) {
      int t4 = lane;
      float gg = ((t4 & 8) ? g1[6] : g0[6]) * ((t4 & 4) ? g1[7] : g0[7])
               * ((t4 & 2) ? g1[8] : g0[8]) * ((t4 & 1) ? g1[9] : g0[9]);
      greg[(size_t)el * 16 + t4] =
          (unsigned short)(h2u((h2){(_Float16)gg, (_Float16)gg}) & 0xFFFF);
    }
    if (lane == 0) {
      out[2 * (size_t)el]     = bpost[0];
      out[2 * (size_t)el + 1] = bpost[1];
    }
  }
}

// ============ kernel 3: main GEMM [8192x1024]x[1024x1024] + fused epilogue ====
// grid 512 = 64 M-blocks x 8 N-splits; 4 waves of [64 rows x 64 cols] each.
__global__ void __launch_bounds__(256) gemm_kernel(
    const unsigned short* __restrict__ Bswz,
    const unsigned short* __restrict__ glane,
    const unsigned short* __restrict__ greg,
    const float* __restrict__ w0, const float* __restrict__ w1,
    float* __restrict__ out) {
  int bm = blockIdx.x >> 3, bn = blockIdx.x & 7;
  int wvL  = threadIdx.x >> 6;
  int lane = threadIdx.x & 63;
  int wm = wvL >> 1, wn = wvL & 1;
  int l15 = lane & 15, lhi = lane >> 4;
  int rowBase = bm * 128 + wm * 64;           // + mt*16 + (l&15) = A row
  int hh = lhi & 1;                            // greg half
  int gsel = lhi >> 1;                         // glane parity within kt

  // per-mt element row for A-fragments and its greg fragment (K-invariant)
  h2 grf[4][4];
  int eA[4];
#pragma unroll
  for (int mt = 0; mt < 4; ++mt) {
    eA[mt] = rowBase + mt * 16 + l15;
    const uu4* gp = (const uu4*)(greg + (size_t)eA[mt] * 16 + hh * 8);
    uu4 gu = *gp;
    grf[mt][0] = ih2(gu.x); grf[mt][1] = ih2(gu.y);
    grf[mt][2] = ih2(gu.z); grf[mt][3] = ih2(gu.w);
  }

  v4f acc[4][4];
#pragma unroll
  for (int mt = 0; mt < 4; ++mt)
#pragma unroll
    for (int nt = 0; nt < 4; ++nt) acc[mt][nt] = (v4f){0.f, 0.f, 0.f, 0.f};

  int ntG0 = bn * 8 + wn * 4;

#pragma unroll 2
  for (int kt = 0; kt < 32; ++kt) {
    // A fragments: A[row, k] = glane[row][k>>4] * greg[row][k&15]
    v8h af[4];
#pragma unroll
    for (int mt = 0; mt < 4; ++mt) {
      unsigned short gs = glane[(size_t)eA[mt] * 64 + kt * 2 + gsel];
      h2 g2 = ih2((int)((unsigned)gs | ((unsigned)gs << 16)));
      uu4 au;
      au.x = h2u(g2 * grf[mt][0]);
      au.y = h2u(g2 * grf[mt][1]);
      au.z = h2u(g2 * grf[mt][2]);
      au.w = h2u(g2 * grf[mt][3]);
      af[mt] = __builtin_bit_cast(v8h, au);
    }
    // B fragments: one dwordx4 per tile, pre-swizzled layout
    v8h bf[4];
#pragma unroll
    for (int nt = 0; nt < 4; ++nt) {
      const uu4* bp = (const uu4*)(Bswz + (((size_t)(ntG0 + nt) * 32 + kt) << 9)
                                   + (size_t)lane * 8);
      bf[nt] = __builtin_bit_cast(v8h, *bp);
    }
#pragma unroll
    for (int mt = 0; mt < 4; ++mt)
#pragma unroll
      for (int nt = 0; nt < 4; ++nt)
        acc[mt][nt] = __builtin_amdgcn_mfma_f32_16x16x32_f16(
            af[mt], bf[nt], acc[mt][nt], 0, 0, 0);
  }

  // fused epilogue: out[e] += sum_n q(C[e,n]) * w{0,1}[n]
  float wa[4], wb[4];
#pragma unroll
  for (int nt = 0; nt < 4; ++nt) {
    int n = bn * 128 + wn * 64 + nt * 16 + l15;
    wa[nt] = w0[n]; wb[nt] = w1[n];
  }
#pragma unroll
  for (int mt = 0; mt < 4; ++mt) {
#pragma unroll
    for (int j = 0; j < 4; ++j) {
      float p0 = 0.f, p1 = 0.f;
#pragma unroll
      for (int nt = 0; nt < 4; ++nt) {
        float c = acc[mt][nt][j];
        float q = c * c;
        p0 += q * wa[nt];
        p1 += q * wb[nt];
      }
      p0 += __shfl_xor(p0, 1, 64); p1 += __shfl_xor(p1, 1, 64);
      p0 += __shfl_xor(p0, 2, 64); p1 += __shfl_xor(p1, 2, 64);
      p0 += __shfl_xor(p0, 4, 64); p1 += __shfl_xor(p1, 4, 64);
      p0 += __shfl_xor(p0, 8, 64); p1 += __shfl_xor(p1, 8, 64);
      if (l15 == 0) {
        int e = rowBase + mt * 16 + lhi * 4 + j;   // C row m = (l>>4)*4 + j
        atomicAdd(&out[2 * (size_t)e],     p0);
        atomicAdd(&out[2 * (size_t)e + 1], p1);
      }
    }
  }
}

extern "C" void kernel_launch(void* const* d_in, const int* in_sizes, int n_in,
                              void* d_out, int out_size, void* d_ws, size_t ws_size,
                              hipStream_t stream) {
  const float* inp   = (const float*)d_in[0];
  const float* Wred  = (const float*)d_in[1];
  const float* bred  = (const float*)d_in[2];
  const float* qp    = (const float*)d_in[3];
  const float* Wpost = (const float*)d_in[4];
  const float* bpost = (const float*)d_in[5];
  float* out = (float*)d_out;

  unsigned short* Bswz  = (unsigned short*)d_ws;                          // 2 MB
  unsigned short* glane = (unsigned short*)((char*)d_ws + (2u << 20));    // 1 MB
  unsigned short* greg  = (unsigned short*)((char*)d_ws + (3u << 20));    // 256 KB
  float* w0 = (float*)((char*)d_ws + (3u << 20) + (256u << 10));          // 4 KB
  float* w1 = w0 + 1024;

  int B = in_sizes[0] / 512;  // 8192

  build_kernel<<<256, 256, 0, stream>>>(qp, Wpost, Bswz, w0, w1);
  glgr_kernel<<<(B * 32) / 256, 256, 0, stream>>>(inp, Wred, bred, bpost,
                                                  glane, greg, out);
  gemm_kernel<<<(B / 128) * 8, 256, 0, stream>>>(Bswz, glane, greg, w0, w1, out);
}

// Round 9
// 122.990 us; speedup vs baseline: 1.0785x; 1.0785x over previous
//
#include <hip/hip_runtime.h>
#include <math.h>

#define QDEPTH 6

typedef _Float16 h2 __attribute__((ext_vector_type(2)));
typedef _Float16 v8h __attribute__((ext_vector_type(8)));
typedef float    v4f __attribute__((ext_vector_type(4)));
typedef unsigned uu4 __attribute__((ext_vector_type(4)));

__device__ __forceinline__ int   h2i(h2 v)  { return __builtin_bit_cast(int, v); }
__device__ __forceinline__ h2    ih2(int v) { return __builtin_bit_cast(h2, v); }
__device__ __forceinline__ unsigned h2u(h2 v) { return __builtin_bit_cast(unsigned, v); }

__device__ __forceinline__ h2 bper(int addr, h2 v) {
  return ih2(__builtin_amdgcn_ds_bpermute(addr, h2i(v)));
}

template<int CTRL>
__device__ __forceinline__ h2 dpph(h2 v) {
  int i = h2i(v);
  return ih2(__builtin_amdgcn_update_dpp(i, i, CTRL, 0xF, 0xF, true));
}

template<int CTRL>
__device__ __forceinline__ float dpp_add0(float v) {
  int i = __float_as_int(v);
  int r = __builtin_amdgcn_update_dpp(0, i, CTRL, 0xF, 0xF, false);
  return v + __int_as_float(r);
}

__device__ __forceinline__ float wave_sum(float v) {
  v = dpp_add0<0x111>(v);
  v = dpp_add0<0x112>(v);
  v = dpp_add0<0x114>(v);
  v = dpp_add0<0x118>(v);
  v = dpp_add0<0x142>(v);
  v = dpp_add0<0x143>(v);
  return v;
}

__device__ __forceinline__ float bcast63(float v) {
  return __int_as_float(__builtin_amdgcn_readlane(__float_as_int(v), 63));
}

__device__ __forceinline__ void pl32s(int& a, int& b) {
  asm("v_permlane32_swap_b32 %0, %1" : "+v"(a), "+v"(b));
}
__device__ __forceinline__ void pl16s(int& a, int& b) {
  asm("v_permlane16_swap_b32 %0, %1" : "+v"(a), "+v"(b));
}

// ---- circuit-layer engine (verified R5-R8) ----
__device__ __forceinline__ void apply_layers(h2 (&x)[8], const unsigned* sco,
                                             int lane, int addrP, int addrX4,
                                             bool cb1) {
  for (int k = 0; k < QDEPTH; ++k) {
    const unsigned* L = sco + k * 29;
#pragma unroll
    for (int i = 0; i < 8; ++i) x[i] = bper(addrP, x[i]);
    { h2 t = x[4]; x[4] = x[6]; x[6] = t; t = x[5]; x[5] = x[7]; x[7] = t; }
    { h2 t = x[2]; x[2] = x[3]; x[3] = t; t = x[6]; x[6] = x[7]; x[7] = t; }
    { h2 cc9 = ih2(L[27]), ms9 = ih2(L[28]);
#pragma unroll
      for (int i = 0; i < 8; ++i) {
        h2 t = __builtin_shufflevector(x[i], x[i], 1, 0);
        bool flg = (i == 1 || i == 2 || i == 5 || i == 6);
        x[i] = flg ? (h2)(t * cc9 + x[i] * ms9) : (h2)(x[i] * cc9 + t * ms9);
      } }
    { h2 cc6 = ih2(L[18]), ss6 = ih2(L[19]), ns6 = ih2(L[20]);
      h2 AA = cb1 ? ns6 : cc6;
      h2 BB = cb1 ? cc6 : ns6;
      h2 CC = cb1 ? cc6 : ss6;
      h2 DD = cb1 ? ss6 : cc6;
#pragma unroll
      for (int i = 0; i < 4; ++i) {
        h2 u = x[i], w = x[i + 4];
        x[i]     = u * AA + w * BB;
        x[i + 4] = u * CC + w * DD;
      } }
    { h2 cc7 = ih2(L[21]), ss7 = ih2(L[22]), ns7 = ih2(L[23]);
#pragma unroll
      for (int i = 0; i < 8; ++i) if (!(i & 2)) {
        h2 u = x[i], w = x[i | 2];
        x[i]     = u * cc7 + w * ns7;
        x[i | 2] = w * cc7 + u * ss7;
      } }
    { h2 cc8 = ih2(L[24]), ss8 = ih2(L[25]), ns8 = ih2(L[26]);
#pragma unroll
      for (int i = 0; i < 8; ++i) if (!(i & 1)) {
        h2 u = x[i], w = x[i | 1];
        x[i]     = u * cc8 + w * ns8;
        x[i | 1] = w * cc8 + u * ss8;
      } }
    { h2 cc0 = ih2(L[0]), ss0 = ih2(L[1]), ns0 = ih2(L[2]);
#pragma unroll
      for (int j = 0; j < 4; ++j) {
        int a = h2i(x[2 * j]), b = h2i(x[2 * j + 1]);
        pl32s(a, b);
        h2 u = ih2(a), v = ih2(b);
        h2 nu = u * cc0 + v * ns0;
        h2 nv = v * cc0 + u * ss0;
        int na = h2i(nu), nb = h2i(nv);
        pl32s(na, nb);
        x[2 * j] = ih2(na); x[2 * j + 1] = ih2(nb);
      } }
    { h2 cc1 = ih2(L[3]), ss1 = ih2(L[4]), ns1 = ih2(L[5]);
#pragma unroll
      for (int j = 0; j < 4; ++j) {
        int a = h2i(x[2 * j]), b = h2i(x[2 * j + 1]);
        pl16s(a, b);
        h2 u = ih2(a), v = ih2(b);
        h2 nu = u * cc1 + v * ns1;
        h2 nv = v * cc1 + u * ss1;
        int na = h2i(nu), nb = h2i(nv);
        pl16s(na, nb);
        x[2 * j] = ih2(na); x[2 * j + 1] = ih2(nb);
      } }
    { h2 cc2 = ih2(L[6]), ss2 = ih2(L[7]), ns2 = ih2(L[8]);
      h2 gg = (lane & 8) ? ss2 : ns2;
#pragma unroll
      for (int i = 0; i < 8; ++i) {
        h2 p = dpph<0x128>(x[i]);
        x[i] = x[i] * cc2 + p * gg;
      } }
    { h2 cc3 = ih2(L[9]), ss3 = ih2(L[10]), ns3 = ih2(L[11]);
      h2 gg = (lane & 4) ? ss3 : ns3;
#pragma unroll
      for (int i = 0; i < 8; ++i) {
        h2 p = bper(addrX4, x[i]);
        x[i] = x[i] * cc3 + p * gg;
      } }
    { h2 cc4 = ih2(L[12]), ss4 = ih2(L[13]), ns4 = ih2(L[14]);
      h2 gg = (lane & 2) ? ss4 : ns4;
#pragma unroll
      for (int i = 0; i < 8; ++i) {
        h2 p = dpph<0x4E>(x[i]);
        x[i] = x[i] * cc4 + p * gg;
      } }
    { h2 cc5 = ih2(L[15]), ss5 = ih2(L[16]), ns5 = ih2(L[17]);
      h2 gg = (lane & 1) ? ss5 : ns5;
#pragma unroll
      for (int i = 0; i < 8; ++i) {
        h2 p = dpph<0xB1>(x[i]);
        x[i] = x[i] * cc5 + p * gg;
      } }
  }
}

__device__ __forceinline__ void fill_sco(const float* qp, unsigned* sco) {
  int t = threadIdx.x;
  if (t < 60) {
    int k = t / 10, w = t % 10;
    float ang = qp[(k + 1) * 10 + w] * 0.5f;
    float c = __cosf(ang), s = __sinf(ang);
    _Float16 ch = (_Float16)c, sh = (_Float16)s, nh = (_Float16)(-s);
    if (w < 9) {
      sco[k * 29 + w * 3 + 0] = h2u((h2){ch, ch});
      sco[k * 29 + w * 3 + 1] = h2u((h2){sh, sh});
      sco[k * 29 + w * 3 + 2] = h2u((h2){nh, nh});
    } else {
      sco[k * 29 + 27] = h2u((h2){ch, ch});
      sco[k * 29 + 28] = h2u((h2){nh, sh});
    }
  }
}

// ============ kernel 1 (FUSED): blocks 0..255 build U^T; blocks 256+ tables ==
__global__ void __launch_bounds__(256) prep_kernel(
    const float* __restrict__ qp, const float* __restrict__ Wpost,
    const float* __restrict__ inp, const float* __restrict__ Wred,
    const float* __restrict__ bred, const float* __restrict__ bpost,
    unsigned short* __restrict__ Bswz,
    unsigned short* __restrict__ glaneP,   // [2][8192][32]
    unsigned short* __restrict__ greg,     // [8192][16]
    float* __restrict__ w0, float* __restrict__ w1,
    float* __restrict__ out) {
  int lane = threadIdx.x & 63;

  if (blockIdx.x < 256) {
    // ---------- builder: one basis state per wave ----------
    __shared__ unsigned sco[QDEPTH * 29];
    fill_sco(qp, sco);
    __syncthreads();

    int i = blockIdx.x * 4 + (threadIdx.x >> 6);  // basis 0..1023

    if (blockIdx.x == 0) {
      for (int n = threadIdx.x; n < 1024; n += 256) {
        float a0 = 0.f, a1 = 0.f;
#pragma unroll
        for (int w = 0; w < 10; ++w) {
          float sg = ((n >> (9 - w)) & 1) ? -1.f : 1.f;
          a0 += sg * Wpost[w];
          a1 += sg * Wpost[10 + w];
        }
        w0[n] = a0; w1[n] = a1;
      }
    }

    int o = lane ^ (((lane >> 4) & 1) << 3) ^ (((lane >> 2) & 1) << 1);
    int psrc = o ^ (((o >> 5) & 1) << 4) ^ (((o >> 3) & 1) << 2) ^ ((o >> 1) & 1);
    int addrP = psrc << 2, addrX4 = (lane ^ 4) << 2;
    bool cb1 = lane & 1;

    h2 x[8];
#pragma unroll
    for (int r = 0; r < 8; ++r) {
      int base = lane * 16 + 2 * r;
      x[r] = (h2){ (_Float16)(base == i ? 1.f : 0.f),
                   (_Float16)(base + 1 == i ? 1.f : 0.f) };
    }
    apply_layers(x, sco, lane, addrP, addrX4, cb1);

    int kt = i >> 5, kk = i & 31;
    int jj = kk & 7, hi16 = (kk >> 3) << 4;
    size_t tbase = ((size_t)(lane * 32 + kt)) << 9;
#pragma unroll
    for (int r = 0; r < 8; ++r) {
      unsigned u = h2u(x[r]);
      Bswz[tbase + (size_t)((hi16 | (2 * r)) * 8 + jj)]     = (unsigned short)(u & 0xFFFF);
      Bswz[tbase + (size_t)((hi16 | (2 * r + 1)) * 8 + jj)] = (unsigned short)(u >> 16);
    }
  } else {
    // ---------- glgr: pre-GEMM + product-state factor tables ----------
    int wv = (blockIdx.x - 256) * 4 + (threadIdx.x >> 6);

    const float4* rA = (const float4*)(inp + (size_t)(2 * wv) * 512);
    const float4* rB = (const float4*)(inp + (size_t)(2 * wv + 1) * 512);
    float4 A0 = rA[lane], A1 = rA[lane + 64];
    float4 B0 = rB[lane], B1 = rB[lane + 64];
    float thA[10], thB[10];
#pragma unroll
    for (int q = 0; q < 10; ++q) {
      const float4* w4 = (const float4*)(Wred + q * 512);
      float4 w0v = w4[lane], w1v = w4[lane + 64];
      thA[q] = A0.x * w0v.x + A0.y * w0v.y + A0.z * w0v.z + A0.w * w0v.w
             + A1.x * w1v.x + A1.y * w1v.y + A1.z * w1v.z + A1.w * w1v.w;
      thB[q] = B0.x * w0v.x + B0.y * w0v.y + B0.z * w0v.z + B0.w * w0v.w
             + B1.x * w1v.x + B1.y * w1v.y + B1.z * w1v.z + B1.w * w1v.w;
    }

#pragma unroll
    for (int e = 0; e < 2; ++e) {
      int el = 2 * wv + e;
      float g0[10], g1[10];
#pragma unroll
      for (int q = 0; q < 10; ++q) {
        float tot = bcast63(wave_sum(e ? thB[q] : thA[q])) + bred[q];
        float xc = fminf(fmaxf(tot, -15.f), 15.f);
        float u = __expf(2.f * xc);
        float tanhv = (u - 1.f) * __builtin_amdgcn_rcpf(u + 1.f);
        float t = tanhv * 0.78539816339744831f;
        float c = __cosf(t), s = __sinf(t);
        g0[q] = (c - s) * 0.70710678118654752f;
        g1[q] = (c + s) * 0.70710678118654752f;
      }
      float lf = 1.f;
#pragma unroll
      for (int w = 0; w < 6; ++w)
        lf *= ((lane >> (5 - w)) & 1) ? g1[w] : g0[w];
      // parity-split plane: plane p=lane&1 holds k-lane indices {p, p+2, ...}
      glaneP[((size_t)(lane & 1) * 8192 + el) * 32 + (lane >> 1)] =
          (unsigned short)(h2u((h2){(_Float16)lf, (_Float16)lf}) & 0xFFFF);
      if (lane < 16) {
        int t4 = lane;
        float gg = ((t4 & 8) ? g1[6] : g0[6]) * ((t4 & 4) ? g1[7] : g0[7])
                 * ((t4 & 2) ? g1[8] : g0[8]) * ((t4 & 1) ? g1[9] : g0[9]);
        greg[(size_t)el * 16 + t4] =
            (unsigned short)(h2u((h2){(_Float16)gg, (_Float16)gg}) & 0xFFFF);
      }
      if (lane == 0) {
        out[2 * (size_t)el]     = bpost[0];
        out[2 * (size_t)el + 1] = bpost[1];
      }
    }
  }
}

// ============ kernel 2: GEMM + fused epilogue ============
// grid 1024 = 64 M-blocks x 16 N-splits; block = 4 waves (2m x 2n);
// wave-tile = 64 rows x 32 cols, K=1024 full.
__global__ void __launch_bounds__(256, 4) gemm_kernel(
    const unsigned short* __restrict__ Bswz,
    const unsigned short* __restrict__ glaneP,
    const unsigned short* __restrict__ greg,
    const float* __restrict__ w0, const float* __restrict__ w1,
    float* __restrict__ out) {
  int bm = blockIdx.x >> 4, bn = blockIdx.x & 15;
  int wvL  = threadIdx.x >> 6;
  int lane = threadIdx.x & 63;
  int wm = wvL >> 1, wn = wvL & 1;
  int l15 = lane & 15, lhi = lane >> 4;
  int gsel = lhi >> 1;     // glane parity
  int hh   = lhi & 1;      // greg half
  int rowBase = bm * 128 + wm * 64;
  int ntG0 = bn * 4 + wn * 2;   // global 16-col n-tile base

  int eA[4];
  h2 grf[4][4];
  const uu4* glp[4];
#pragma unroll
  for (int mt = 0; mt < 4; ++mt) {
    eA[mt] = rowBase + mt * 16 + l15;
    const uu4* gp = (const uu4*)(greg + (size_t)eA[mt] * 16 + hh * 8);
    uu4 gu = *gp;
    grf[mt][0] = ih2(gu.x); grf[mt][1] = ih2(gu.y);
    grf[mt][2] = ih2(gu.z); grf[mt][3] = ih2(gu.w);
    glp[mt] = (const uu4*)(glaneP + ((size_t)gsel * 8192 + eA[mt]) * 32);
  }

  v4f acc[4][2];
#pragma unroll
  for (int mt = 0; mt < 4; ++mt) {
    acc[mt][0] = (v4f){0.f, 0.f, 0.f, 0.f};
    acc[mt][1] = (v4f){0.f, 0.f, 0.f, 0.f};
  }

#pragma unroll 1
  for (int c = 0; c < 4; ++c) {
    // one dwordx4 per mt covers 8 kt of A scalars (coalesced)
    uu4 gu[4];
#pragma unroll
    for (int mt = 0; mt < 4; ++mt) gu[mt] = glp[mt][c];
#pragma unroll
    for (int t = 0; t < 8; ++t) {
      int kt = c * 8 + t;
      // B fragments: 1 dwordx4 each, fully coalesced, L2-resident
      v8h bf0, bf1;
      {
        const uu4* bp0 = (const uu4*)(Bswz + (((size_t)(ntG0)     * 32 + kt) << 9)) + lane;
        const uu4* bp1 = (const uu4*)(Bswz + (((size_t)(ntG0 + 1) * 32 + kt) << 9)) + lane;
        bf0 = __builtin_bit_cast(v8h, *bp0);
        bf1 = __builtin_bit_cast(v8h, *bp1);
      }
      unsigned sel = (t & 1) ? 0x03020302u : 0x01000100u;
#pragma unroll
      for (int mt = 0; mt < 4; ++mt) {
        unsigned word = gu[mt][t >> 1];
        h2 g2 = ih2((int)__builtin_amdgcn_perm(word, word, sel));
        uu4 au;
        au.x = h2u(g2 * grf[mt][0]);
        au.y = h2u(g2 * grf[mt][1]);
        au.z = h2u(g2 * grf[mt][2]);
        au.w = h2u(g2 * grf[mt][3]);
        v8h af = __builtin_bit_cast(v8h, au);
        acc[mt][0] = __builtin_amdgcn_mfma_f32_16x16x32_f16(af, bf0, acc[mt][0], 0, 0, 0);
        acc[mt][1] = __builtin_amdgcn_mfma_f32_16x16x32_f16(af, bf1, acc[mt][1], 0, 0, 0);
      }
    }
  }

  // fused epilogue: out[e] += sum_n C[e,n]^2 * w{0,1}[n]
  float wa[2], wb[2];
#pragma unroll
  for (int nt = 0; nt < 2; ++nt) {
    int n = bn * 64 + wn * 32 + nt * 16 + l15;
    wa[nt] = w0[n]; wb[nt] = w1[n];
  }
#pragma unroll
  for (int mt = 0; mt < 4; ++mt) {
#pragma unroll
    for (int j = 0; j < 4; ++j) {
      float c0 = acc[mt][0][j], c1 = acc[mt][1][j];
      float p0 = c0 * c0 * wa[0] + c1 * c1 * wa[1];
      float p1 = c0 * c0 * wb[0] + c1 * c1 * wb[1];
      p0 += __shfl_xor(p0, 1, 64); p1 += __shfl_xor(p1, 1, 64);
      p0 += __shfl_xor(p0, 2, 64); p1 += __shfl_xor(p1, 2, 64);
      p0 += __shfl_xor(p0, 4, 64); p1 += __shfl_xor(p1, 4, 64);
      p0 += __shfl_xor(p0, 8, 64); p1 += __shfl_xor(p1, 8, 64);
      if (l15 == 0) {
        int e = rowBase + mt * 16 + lhi * 4 + j;   // C row = (lane>>4)*4 + j
        atomicAdd(&out[2 * (size_t)e],     p0);
        atomicAdd(&out[2 * (size_t)e + 1], p1);
      }
    }
  }
}

extern "C" void kernel_launch(void* const* d_in, const int* in_sizes, int n_in,
                              void* d_out, int out_size, void* d_ws, size_t ws_size,
                              hipStream_t stream) {
  const float* inp   = (const float*)d_in[0];
  const float* Wred  = (const float*)d_in[1];
  const float* bred  = (const float*)d_in[2];
  const float* qp    = (const float*)d_in[3];
  const float* Wpost = (const float*)d_in[4];
  const float* bpost = (const float*)d_in[5];
  float* out = (float*)d_out;

  unsigned short* Bswz   = (unsigned short*)d_ws;                        // 2 MB
  unsigned short* glaneP = (unsigned short*)((char*)d_ws + (2u << 20));  // 1 MB (2 planes)
  unsigned short* greg   = (unsigned short*)((char*)d_ws + (3u << 20));  // 256 KB
  float* w0 = (float*)((char*)d_ws + (3u << 20) + (256u << 10));         // 4 KB
  float* w1 = w0 + 1024;

  int B = in_sizes[0] / 512;  // 8192

  // fused: 256 builder blocks + B/8 table blocks
  prep_kernel<<<256 + (B * 32) / 256, 256, 0, stream>>>(
      qp, Wpost, inp, Wred, bred, bpost, Bswz, glaneP, greg, w0, w1, out);
  gemm_kernel<<<(B / 128) * 16, 256, 0, stream>>>(Bswz, glaneP, greg, w0, w1, out);
}